// Round 4
// baseline (533.568 us; speedup 1.0000x reference)
//
#include <hip/hip_runtime.h>
#include <math.h>

#define B_   64
#define N_   1024
#define FIN_ 256
#define FO_  64

typedef __attribute__((ext_vector_type(4))) float f32x4;
typedef __attribute__((ext_vector_type(8))) short short8;

__device__ __forceinline__ unsigned fbits(float f){ union{float f;unsigned u;}v; v.f=f; return v.u; }
__device__ __forceinline__ float bcast(unsigned u){ union{unsigned u;float f;}v; v.u=u; return v.f; }
__device__ __forceinline__ float bf2f(unsigned short h){ return bcast(((unsigned)h)<<16); }
// truncate-split: hi = x with low 16 mantissa bits zeroed (exactly representable bf16),
// lo = bf16_trunc(x - hi). hi+lo matches x to ~2^-16 rel; the compensated 3-term MFMA
// (hi*hi + hi*lo + lo*hi) is f32-equivalent.
__device__ __forceinline__ float hi_part(float x){ return bcast(fbits(x) & 0xffff0000u); }
__device__ __forceinline__ unsigned pack_hi(float x0, float x1){   // [bf(x0) | bf(x1)<<16]
    return (fbits(x1) & 0xffff0000u) | (fbits(x0) >> 16);
}

union U8 { unsigned u[4]; short8 s8; };

// ---------------------------------------------------------------------------
// k0: transpose + trunc-split W[256][64] -> WThi/WTlo[64 f][256 k] bf16.
// ---------------------------------------------------------------------------
__global__ void k0_wt(const float* __restrict__ W,
                      unsigned short* __restrict__ WThi,
                      unsigned short* __restrict__ WTlo)
{
    const int idx = blockIdx.x * 256 + threadIdx.x;   // 0..16383
    const int k = idx >> 6, f = idx & 63;
    const float w = W[idx];
    const float hf = hi_part(w);
    WThi[f * FIN_ + k] = (unsigned short)(fbits(w) >> 16);
    WTlo[f * FIN_ + k] = (unsigned short)(fbits(w - hf) >> 16);
}

// ---------------------------------------------------------------------------
// k1: h = input @ W via split-bf16 MFMA, NO main-loop LDS/barriers.
// A-frags: direct f32 global loads (lane (lm,lk) reads row wm0+lm, k-slice
// lk*8; wave instr = 16 rows x 128 B contiguous) + in-register trunc-split.
// B-frags: direct short8 loads from WThi/WTlo (64 KB, L1/L2-hot).
// Epilogue: e2 shuffle-reduce + LDS transpose -> hbT/hrT[b][f][j] bf16.
// ---------------------------------------------------------------------------
__global__ __launch_bounds__(256, 4) void k1_hproj(
    const float* __restrict__ input,
    const unsigned short* __restrict__ WThi,
    const unsigned short* __restrict__ WTlo,
    const float* __restrict__ a,
    unsigned short* __restrict__ hbT,
    unsigned short* __restrict__ hrT,
    float* __restrict__ e2)
{
    __shared__ unsigned short eb[64 * 72];
    __shared__ unsigned short er[64 * 72];

    const int t  = threadIdx.x;
    const int lm = t & 15, lk = (t >> 4) & 3, wm0 = (t >> 6) * 16;
    const int r0 = blockIdx.x * 64;
    const int b  = blockIdx.x >> 4;
    const int jb = r0 & (N_ - 1);

    const float* arow = input + (size_t)(r0 + wm0 + lm) * FIN_;

    f32x4 acc[4] = {};
    float4 xa = *reinterpret_cast<const float4*>(&arow[lk * 8]);
    float4 xb = *reinterpret_cast<const float4*>(&arow[lk * 8 + 4]);

    #pragma unroll
    for (int ks = 0; ks < 8; ++ks) {
        // convert current A slice (8 f32 -> ah/al bf16x8)
        const float x[8] = { xa.x, xa.y, xa.z, xa.w, xb.x, xb.y, xb.z, xb.w };
        U8 ah, al;
        #pragma unroll
        for (int p = 0; p < 4; ++p) {
            const float f0 = x[2 * p], f1 = x[2 * p + 1];
            ah.u[p] = pack_hi(f0, f1);
            al.u[p] = pack_hi(f0 - hi_part(f0), f1 - hi_part(f1));
        }
        if (ks < 7) {   // prefetch next A slice while MFMAs run
            xa = *reinterpret_cast<const float4*>(&arow[(ks + 1) * 32 + lk * 8]);
            xb = *reinterpret_cast<const float4*>(&arow[(ks + 1) * 32 + lk * 8 + 4]);
        }
        #pragma unroll
        for (int nt = 0; nt < 4; ++nt) {
            const int off = (nt * 16 + lm) * FIN_ + ks * 32 + lk * 8;
            const short8 bh = *reinterpret_cast<const short8*>(&WThi[off]);
            const short8 bl = *reinterpret_cast<const short8*>(&WTlo[off]);
            acc[nt] = __builtin_amdgcn_mfma_f32_16x16x32_bf16(ah.s8, bh, acc[nt], 0, 0, 0);
            acc[nt] = __builtin_amdgcn_mfma_f32_16x16x32_bf16(ah.s8, bl, acc[nt], 0, 0, 0);
            acc[nt] = __builtin_amdgcn_mfma_f32_16x16x32_bf16(al.s8, bh, acc[nt], 0, 0, 0);
        }
    }

    // epilogue: e2 = h . a2 (shuffle over lm lanes) + split-h into LDS
    float ap[4];
    #pragma unroll
    for (int nt = 0; nt < 4; ++nt) ap[nt] = a[FO_ + nt * 16 + lm];

    #pragma unroll
    for (int reg = 0; reg < 4; ++reg) {
        const int row = wm0 + lk * 4 + reg;          // C layout: row=(l>>4)*4+reg
        float e2p = 0.f;
        #pragma unroll
        for (int nt = 0; nt < 4; ++nt) {
            const float hv = acc[nt][reg];
            e2p += hv * ap[nt];
            const float hf = hi_part(hv);
            const int f = nt * 16 + lm;              // C layout: col=l&15
            eb[f * 72 + row] = (unsigned short)(fbits(hv) >> 16);
            er[f * 72 + row] = (unsigned short)(fbits(hv - hf) >> 16);
        }
        e2p += __shfl_xor(e2p, 1);
        e2p += __shfl_xor(e2p, 2);
        e2p += __shfl_xor(e2p, 4);
        e2p += __shfl_xor(e2p, 8);
        if (lm == 0) e2[r0 + row] = e2p;
    }
    __syncthreads();

    // coalesced transposed store: hbT/hrT[(b*64+f)*1024 + jb + 0..63]
    {
        const int f = t >> 2, seg = t & 3;
        const size_t gb = ((size_t)(b * FO_ + f)) * N_ + jb + seg * 16;
        *reinterpret_cast<short8*>(&hbT[gb]) =
            *reinterpret_cast<const short8*>(&eb[f * 72 + seg * 16]);
        *reinterpret_cast<short8*>(&hbT[gb + 8]) =
            *reinterpret_cast<const short8*>(&eb[f * 72 + seg * 16 + 8]);
        *reinterpret_cast<short8*>(&hrT[gb]) =
            *reinterpret_cast<const short8*>(&er[f * 72 + seg * 16]);
        *reinterpret_cast<short8*>(&hrT[gb + 8]) =
            *reinterpret_cast<const short8*>(&er[f * 72 + seg * 16 + 8]);
    }
}

// ---------------------------------------------------------------------------
// k2: fused masked softmax attention + PV + ELU. NO LDS, NO barriers.
// Lane (lm,lk) of wave wv computes its OWN A-frag weights:
//   row i = i0+wv*16+lm, j-slice = jt+lk*8..+8
//   e = relu(S1*h[i][j>>4] + e2[j]); w = adj ? exp(e) : 0  (single pass; no
//   max needed: unmasked e in [0,~45]; masked weight exactly 0 as reference)
// trunc-split w -> whi/wlo; B-frags = direct short8 from hbT/hrT (L1/L2-hot).
// den = f32 sum of exactly (hi+lo) -> softmax ratios preserved vs numerator.
// adj prefetch distance-1; waves free-run (no sync), 16+ waves/CU saturate BW.
// ---------------------------------------------------------------------------
__global__ __launch_bounds__(256, 4) void k2_attn(
    const unsigned short* __restrict__ hbT,
    const unsigned short* __restrict__ hrT,
    const int*   __restrict__ adj,
    const float* __restrict__ a,
    const float* __restrict__ e2,
    float* __restrict__ out)
{
    const int t  = threadIdx.x;
    const int lm = t & 15, lk = (t >> 4) & 3, wm0 = (t >> 6) * 16;
    const int b  = blockIdx.y;
    const int i0 = blockIdx.x * 64;
    const int irow = i0 + wm0 + lm;

    const int*   adjrow = adj + ((size_t)b * N_ + irow) * N_;
    const float* e2b    = e2 + (size_t)b * N_;
    const unsigned short* hbTb = hbT + (size_t)b * FO_ * N_;
    const unsigned short* hrTb = hrT + (size_t)b * FO_ * N_;

    float S1 = 0.f;
    #pragma unroll
    for (int f = 0; f < FO_; f += 4) {
        const float4 av = *reinterpret_cast<const float4*>(&a[f]);
        S1 += av.x + av.y + av.z + av.w;
    }

    f32x4 acc[4] = {};
    float den = 0.f;

    int4 aC0 = *reinterpret_cast<const int4*>(&adjrow[lk * 8]);
    int4 aC1 = *reinterpret_cast<const int4*>(&adjrow[lk * 8 + 4]);

    #pragma unroll 1
    for (int tile = 0; tile < 32; ++tile) {
        const int jt = tile * 32;
        int4 aN0, aN1;
        if (tile < 31) {   // HBM prefetch for next tile, in flight during MFMA
            aN0 = *reinterpret_cast<const int4*>(&adjrow[jt + 32 + lk * 8]);
            aN1 = *reinterpret_cast<const int4*>(&adjrow[jt + 32 + lk * 8 + 4]);
        }
        // L2-hot operands
        const float4 ea = *reinterpret_cast<const float4*>(&e2b[jt + lk * 8]);
        const float4 eb2 = *reinterpret_cast<const float4*>(&e2b[jt + lk * 8 + 4]);
        const int g = (jt >> 4) + (lk >> 1);          // j>>4, constant per lane slice
        const float c2 = bf2f(hbTb[(size_t)g * N_ + irow]) +
                         bf2f(hrTb[(size_t)g * N_ + irow]);
        const float cg = S1 * c2;

        const int   aa[8] = { aC0.x, aC0.y, aC0.z, aC0.w, aC1.x, aC1.y, aC1.z, aC1.w };
        const float ee[8] = { ea.x, ea.y, ea.z, ea.w, eb2.x, eb2.y, eb2.z, eb2.w };
        float hf[8], lf[8];
        #pragma unroll
        for (int d = 0; d < 8; ++d) {
            const float ev = fmaxf(cg + ee[d], 0.f);
            const float w  = aa[d] ? __expf(ev) : 0.f;
            hf[d] = hi_part(w);
            lf[d] = w - hf[d];
            den += hf[d] + hi_part(lf[d]);            // == bf2f(whi)+bf2f(wlo) exactly
        }
        U8 whi, wlo;
        #pragma unroll
        for (int p = 0; p < 4; ++p) {
            whi.u[p] = pack_hi(hf[2 * p], hf[2 * p + 1]);
            wlo.u[p] = pack_hi(lf[2 * p], lf[2 * p + 1]);
        }

        #pragma unroll
        for (int nt = 0; nt < 4; ++nt) {
            const size_t off = (size_t)(nt * 16 + lm) * N_ + jt + lk * 8;
            const short8 bh = *reinterpret_cast<const short8*>(&hbTb[off]);
            const short8 br = *reinterpret_cast<const short8*>(&hrTb[off]);
            acc[nt] = __builtin_amdgcn_mfma_f32_16x16x32_bf16(whi.s8, bh, acc[nt], 0, 0, 0);
            acc[nt] = __builtin_amdgcn_mfma_f32_16x16x32_bf16(whi.s8, br, acc[nt], 0, 0, 0);
            acc[nt] = __builtin_amdgcn_mfma_f32_16x16x32_bf16(wlo.s8, bh, acc[nt], 0, 0, 0);
        }
        aC0 = aN0; aC1 = aN1;
    }

    // row-sum reduction: lanes differing in bits 4-5 (lk) hold j-slices of row lm
    den += __shfl_xor(den, 16);
    den += __shfl_xor(den, 32);

    #pragma unroll
    for (int reg = 0; reg < 4; ++reg) {
        const int m = lk * 4 + reg;                   // C layout row within wave
        const float dm = __shfl(den, m);              // lane m holds den of row m
        const float inv = 1.0f / dm;
        #pragma unroll
        for (int nt = 0; nt < 4; ++nt) {
            const float x = acc[nt][reg] * inv;
            const float y = (x > 0.f) ? x : expm1f(x);
            out[((size_t)b * N_ + i0 + wm0 + m) * FO_ + nt * 16 + lm] = y;
        }
    }
}

extern "C" void kernel_launch(void* const* d_in, const int* in_sizes, int n_in,
                              void* d_out, int out_size, void* d_ws, size_t ws_size,
                              hipStream_t stream) {
    const float* input = (const float*)d_in[0];   // [64][1024][256] f32
    const int*   adj   = (const int*)d_in[1];     // [64][1024][1024] i32
    const float* W     = (const float*)d_in[2];   // [256][64] f32
    const float* a     = (const float*)d_in[3];   // [128] f32
    float* out = (float*)d_out;                   // [64][1024][64] f32

    char* ws = (char*)d_ws;
    unsigned short* hbT  = (unsigned short*)(ws);                       // 8 MiB
    unsigned short* hrT  = (unsigned short*)(ws + (8u << 20));          // 8 MiB
    float*          e2   = (float*)(ws + (16u << 20));                  // 256 KiB
    unsigned short* WThi = (unsigned short*)(ws + (16u << 20) + (256u << 10));
    unsigned short* WTlo = WThi + FO_ * FIN_;

    k0_wt   <<<dim3(64),              dim3(256), 0, stream>>>(W, WThi, WTlo);
    k1_hproj<<<dim3((B_ * N_) / 64),  dim3(256), 0, stream>>>(input, WThi, WTlo, a, hbT, hrT, e2);
    k2_attn <<<dim3(N_ / 64, B_),     dim3(256), 0, stream>>>(hbT, hrT, adj, a, e2, out);
}

// Round 5
// 447.434 us; speedup vs baseline: 1.1925x; 1.1925x over previous
//
#include <hip/hip_runtime.h>
#include <math.h>

#define B_   64
#define N_   1024
#define FIN_ 256
#define FO_  64

typedef __attribute__((ext_vector_type(4))) float f32x4;
typedef __attribute__((ext_vector_type(8))) short short8;

__device__ __forceinline__ unsigned fbits(float f){ union{float f;unsigned u;}v; v.f=f; return v.u; }
__device__ __forceinline__ float bcast(unsigned u){ union{unsigned u;float f;}v; v.u=u; return v.f; }
// truncate-split: hi = x with low 16 mantissa bits zeroed; lo = bf16_trunc(x-hi).
// (hi+lo) matches x to ~2^-16 rel; 3-term MFMA (hi*hi + hi*lo + lo*hi) is f32-equivalent.
__device__ __forceinline__ float hi_part(float x){ return bcast(fbits(x) & 0xffff0000u); }
__device__ __forceinline__ unsigned pack_hi(float x0, float x1){   // [bf(x0) | bf(x1)<<16]
    return (fbits(x1) & 0xffff0000u) | (fbits(x0) >> 16);
}
union U8 { unsigned u[4]; short8 s8; };

// ---------------------------------------------------------------------------
// k0: W[256][64] -> fragment-ordered split WTf[hi/lo]: for k1's A-frags.
// idx = ((ks*4+lk)*64 + f)*8 + e  with k = ks*32 + lk*8 + e.
// k1's A-frag load becomes 4-segment contiguous (16 lanes x 16B per lk chunk).
// ---------------------------------------------------------------------------
__global__ void k0_wt(const float* __restrict__ W,
                      unsigned short* __restrict__ WTfhi,
                      unsigned short* __restrict__ WTflo)
{
    const int tid = blockIdx.x * 256 + threadIdx.x;   // 0..16383
    const int k = tid >> 6, f = tid & 63;
    const float wv = W[tid];
    const int idx = ((((k >> 5) * 4 + ((k >> 3) & 3)) * 64 + f) << 3) + (k & 7);
    WTfhi[idx] = (unsigned short)(fbits(wv) >> 16);
    WTflo[idx] = (unsigned short)(fbits(wv - hi_part(wv)) >> 16);
}

// ---------------------------------------------------------------------------
// k1 (transposed): h^T = W^T @ input^T via split-bf16 MFMA.
//   A = W^T (M=f, frag-ordered global, 4-seg, L2-hot)
//   B = input^T (K=k, N=j): lane's 8 frag elems = 8 consecutive k of ONE input
//       row -> contiguous 32B; lines fully consumed. No LDS, no transpose.
// Outputs: hbT/hrT[b][f][j] (split bf16), c1T[b][f][j] = S1*h^T (f32),
//          e2[b*N+j] = h[j,:].a2 (f32). C-layout writes h^T natively.
// ---------------------------------------------------------------------------
__global__ __launch_bounds__(256, 4) void k1_hproj(
    const float* __restrict__ input,
    const unsigned short* __restrict__ WTfhi,
    const unsigned short* __restrict__ WTflo,
    const float* __restrict__ a,
    unsigned short* __restrict__ hbT,
    unsigned short* __restrict__ hrT,
    float* __restrict__ c1T,
    float* __restrict__ e2)
{
    __shared__ float e2L[4][64];
    const int t = threadIdx.x;
    const int l = t & 63, lm = l & 15, lk = l >> 4, w = t >> 6;
    const int r0 = blockIdx.x * 64;          // global j-row base (b*1024+jb)
    const int b = r0 >> 10, jb = r0 & (N_ - 1);

    float S1 = 0.f;
    #pragma unroll
    for (int f = 0; f < FO_; f += 4) {
        const float4 av = *reinterpret_cast<const float4*>(&a[f]);
        S1 += av.x + av.y + av.z + av.w;
    }

    f32x4 acc[4] = {};
    float4 cur[8], nxt[8];
    const float* bbase = input + (size_t)r0 * FIN_;

    auto loadB = [&](float4* dst, int ks) {
        #pragma unroll
        for (int nt = 0; nt < 4; ++nt) {
            const float* p = bbase + (size_t)(nt * 16 + lm) * FIN_ + ks * 32 + lk * 8;
            dst[nt * 2]     = *reinterpret_cast<const float4*>(p);
            dst[nt * 2 + 1] = *reinterpret_cast<const float4*>(p + 4);
        }
    };

    loadB(cur, 0);
    #pragma unroll
    for (int ks = 0; ks < 8; ++ks) {
        if (ks < 7) loadB(nxt, ks + 1);      // HBM prefetch under MFMAs
        const int abase = (((ks * 4 + lk) * 64) + w * 16 + lm) * 8;
        const short8 ahi = *reinterpret_cast<const short8*>(&WTfhi[abase]);
        const short8 alo = *reinterpret_cast<const short8*>(&WTflo[abase]);
        #pragma unroll
        for (int nt = 0; nt < 4; ++nt) {
            const float4 x0 = cur[nt * 2], x1 = cur[nt * 2 + 1];
            const float xs[8] = { x0.x, x0.y, x0.z, x0.w, x1.x, x1.y, x1.z, x1.w };
            U8 bh, bl;
            #pragma unroll
            for (int p = 0; p < 4; ++p) {
                const float f0 = xs[2 * p], f1 = xs[2 * p + 1];
                bh.u[p] = pack_hi(f0, f1);
                bl.u[p] = pack_hi(f0 - hi_part(f0), f1 - hi_part(f1));
            }
            acc[nt] = __builtin_amdgcn_mfma_f32_16x16x32_bf16(ahi, bh.s8, acc[nt], 0, 0, 0);
            acc[nt] = __builtin_amdgcn_mfma_f32_16x16x32_bf16(ahi, bl.s8, acc[nt], 0, 0, 0);
            acc[nt] = __builtin_amdgcn_mfma_f32_16x16x32_bf16(alo, bh.s8, acc[nt], 0, 0, 0);
        }
        if (ks < 7) {
            #pragma unroll
            for (int q = 0; q < 8; ++q) cur[q] = nxt[q];
        }
    }

    // epilogue: C layout row=(l>>4)*4+reg -> f = w*16+lk*4+reg; col=lm -> j
    float a2v[4];
    #pragma unroll
    for (int reg = 0; reg < 4; ++reg) a2v[reg] = a[FO_ + w * 16 + lk * 4 + reg];

    float ep[4] = { 0.f, 0.f, 0.f, 0.f };
    #pragma unroll
    for (int reg = 0; reg < 4; ++reg) {
        const int f = w * 16 + lk * 4 + reg;
        #pragma unroll
        for (int nt = 0; nt < 4; ++nt) {
            const float hv = acc[nt][reg];
            const size_t o = (size_t)(b * FO_ + f) * N_ + jb + nt * 16 + lm;
            hbT[o] = (unsigned short)(fbits(hv) >> 16);
            hrT[o] = (unsigned short)(fbits(hv - hi_part(hv)) >> 16);
            c1T[o] = S1 * hv;
            ep[nt] += hv * a2v[reg];
        }
    }
    #pragma unroll
    for (int nt = 0; nt < 4; ++nt) {
        ep[nt] += __shfl_xor(ep[nt], 16);
        ep[nt] += __shfl_xor(ep[nt], 32);
    }
    if (lk == 0) {
        #pragma unroll
        for (int nt = 0; nt < 4; ++nt) e2L[w][nt * 16 + lm] = ep[nt];
    }
    __syncthreads();
    if (t < 64) e2[r0 + t] = e2L[0][t] + e2L[1][t] + e2L[2][t] + e2L[3][t];
}

// ---------------------------------------------------------------------------
// k2: fused masked softmax attention + PV + ELU (split-bf16 MFMA).
//   e1 collapses: e[b,i,j] = relu(c1[i][j>>4] + e2[j]), c1 = S1*h (f32, from
//   c1T). w = adj ? (pred ? exp(c1)*E2[j] : 1) : 0 with E2 = exp(e2)
//   precomputed once per block (16x fewer exps; relu handled by the pred).
//   No max pass needed (unmasked e in [0,~45]; masked weight exactly 0).
//   Denominator = MFMA(w, ones-frag) -> exact same (whi+wlo) sum as numerator.
// Per block: 64 i-rows x 1024 j; j-tiles of 32; LDS double-buffered weights
// + h-tile with XOR swizzle (T2); 1 barrier/tile; prefetch distance 2.
// adj loads: 8 rows x 128B per instr (8-seg, lines fully consumed).
// XCD-aware block swizzle: each XCD gets 8 whole batches (L2 locality).
// ---------------------------------------------------------------------------
__global__ __launch_bounds__(256, 4) void k2_attn(
    const unsigned short* __restrict__ hbT,
    const unsigned short* __restrict__ hrT,
    const float* __restrict__ c1T,
    const int*   __restrict__ adj,
    const float* __restrict__ e2,
    float* __restrict__ out)
{
    __shared__ unsigned short hlds[2][64 * 64];   // [f][h][32j] shorts, XOR-swz
    __shared__ unsigned short wlds[2][64 * 64];   // [i][h][32j] shorts, XOR-swz
    __shared__ float e2lds[N_];
    __shared__ float E2lds[N_];

    const int t = threadIdx.x;
    const int l = t & 63, lm = l & 15, lk = l >> 4, w = t >> 6;
    const int wm0 = w * 16;

    const int raw = blockIdx.x;                   // nwg=1024, 8 XCDs
    const int wg  = (raw & 7) * 128 + (raw >> 3); // bijective XCD swizzle
    const int b   = wg >> 4;
    const int i0  = (wg & 15) * 64;

    const int la = l & 7, r8 = l >> 3;            // weight-phase j-quad / row
    const int row0 = wm0 + r8, row1 = wm0 + 8 + r8;
    const int gl = la >> 2;
    const int fs = wm0 + (l >> 2), sj = l & 3;    // h-stage: f-row / j-seg

    const size_t badj = (size_t)b * N_ * N_;
    const int* adjr0 = adj + badj + (size_t)(i0 + row0) * N_ + la * 4;
    const int* adjr1 = adj + badj + (size_t)(i0 + row1) * N_ + la * 4;
    const unsigned short* hbTb = hbT + (size_t)b * FO_ * N_;
    const unsigned short* hrTb = hrT + (size_t)b * FO_ * N_;
    const float* c1Tb = c1T + (size_t)b * FO_ * N_;
    const float* e2b  = e2  + (size_t)b * N_;
    float* outb = out + (size_t)b * N_ * FO_;

    f32x4 acc[4] = {};
    f32x4 accd = {};

    int4 areg0, areg1;
    short8 hbreg, hrreg;
    float c1r0, c1r1;

    auto prefetch = [&](int tile) {
        const int jt = tile * 32;
        areg0 = *reinterpret_cast<const int4*>(adjr0 + jt);
        areg1 = *reinterpret_cast<const int4*>(adjr1 + jt);
        hbreg = *reinterpret_cast<const short8*>(&hbTb[(size_t)fs * N_ + jt + sj * 8]);
        hrreg = *reinterpret_cast<const short8*>(&hrTb[(size_t)fs * N_ + jt + sj * 8]);
        const int g = (jt >> 4) + gl;
        c1r0 = c1Tb[(size_t)g * N_ + i0 + row0];
        c1r1 = c1Tb[(size_t)g * N_ + i0 + row1];
    };

    auto phaseW = [&](int tt, int n) {
        const int jt = tt * 32;
        const int swh = (fs & 7) << 3;            // XOR swizzle (T2)
        const int hb0 = fs * 64 + sj * 8;
        *reinterpret_cast<short8*>(&hlds[n][hb0 ^ swh]) = hbreg;
        *reinterpret_cast<short8*>(&hlds[n][(hb0 + 32) ^ swh]) = hrreg;

        const float4 e2q = *reinterpret_cast<const float4*>(&e2lds[jt + la * 4]);
        const float4 E2q = *reinterpret_cast<const float4*>(&E2lds[jt + la * 4]);
        const float eq[4] = { e2q.x, e2q.y, e2q.z, e2q.w };
        const float Eq[4] = { E2q.x, E2q.y, E2q.z, E2q.w };
        #pragma unroll
        for (int i8 = 0; i8 < 2; ++i8) {
            const float c = i8 ? c1r1 : c1r0;
            const int4 av = i8 ? areg1 : areg0;
            const float ec = __expf(c);
            const int aa[4] = { av.x, av.y, av.z, av.w };
            float hfv[4], lfv[4];
            #pragma unroll
            for (int d = 0; d < 4; ++d) {
                const float m  = (c + eq[d] > 0.f) ? ec * Eq[d] : 1.0f;
                const float wv = aa[d] ? m : 0.0f;
                hfv[d] = hi_part(wv);
                lfv[d] = wv - hfv[d];
            }
            uint2 whi, wlo;
            whi.x = pack_hi(hfv[0], hfv[1]); whi.y = pack_hi(hfv[2], hfv[3]);
            wlo.x = pack_hi(lfv[0], lfv[1]); wlo.y = pack_hi(lfv[2], lfv[3]);
            const int row = i8 ? row1 : row0;
            const int sww = (row & 7) << 3;
            const int wb  = row * 64 + la * 4;
            *reinterpret_cast<uint2*>(&wlds[n][wb ^ sww]) = whi;
            *reinterpret_cast<uint2*>(&wlds[n][(wb + 32) ^ sww]) = wlo;
        }
    };

    short8 ones;
    #pragma unroll
    for (int q = 0; q < 8; ++q) ones[q] = (short)0x3F80;  // bf16 1.0

    auto phaseG = [&](int cb) {
        const int arow = wm0 + lm;
        const int swa = (arow & 7) << 3;
        const int ab  = arow * 64 + lk * 8;
        const short8 awh = *reinterpret_cast<const short8*>(&wlds[cb][ab ^ swa]);
        const short8 awl = *reinterpret_cast<const short8*>(&wlds[cb][(ab + 32) ^ swa]);
        accd = __builtin_amdgcn_mfma_f32_16x16x32_bf16(awh, ones, accd, 0, 0, 0);
        accd = __builtin_amdgcn_mfma_f32_16x16x32_bf16(awl, ones, accd, 0, 0, 0);
        #pragma unroll
        for (int nt = 0; nt < 4; ++nt) {
            const int f = nt * 16 + lm;
            const int swb = (f & 7) << 3;
            const int bb  = f * 64 + lk * 8;
            const short8 bh = *reinterpret_cast<const short8*>(&hlds[cb][bb ^ swb]);
            const short8 br = *reinterpret_cast<const short8*>(&hlds[cb][(bb + 32) ^ swb]);
            acc[nt] = __builtin_amdgcn_mfma_f32_16x16x32_bf16(awh, bh, acc[nt], 0, 0, 0);
            acc[nt] = __builtin_amdgcn_mfma_f32_16x16x32_bf16(awh, br, acc[nt], 0, 0, 0);
            acc[nt] = __builtin_amdgcn_mfma_f32_16x16x32_bf16(awl, bh, acc[nt], 0, 0, 0);
        }
    };

    // prologue: e2/E2 stage + pipeline fill
    {
        const float4 ev = *reinterpret_cast<const float4*>(&e2b[t * 4]);
        *reinterpret_cast<float4*>(&e2lds[t * 4]) = ev;
        float4 Ev;
        Ev.x = __expf(ev.x); Ev.y = __expf(ev.y);
        Ev.z = __expf(ev.z); Ev.w = __expf(ev.w);
        *reinterpret_cast<float4*>(&E2lds[t * 4]) = Ev;
    }
    prefetch(0);
    __syncthreads();
    phaseW(0, 0);
    prefetch(1);
    __syncthreads();

    #pragma unroll 1
    for (int tile = 0; tile < 32; ++tile) {
        if (tile < 31) phaseW(tile + 1, (tile + 1) & 1);
        if (tile < 30) prefetch(tile + 2);
        phaseG(tile & 1);
        __syncthreads();
    }

    // epilogue: den from accd (C-layout row = lk*4+reg, replicated over cols)
    #pragma unroll
    for (int reg = 0; reg < 4; ++reg) {
        const int i = i0 + wm0 + lk * 4 + reg;
        const float inv = 1.0f / accd[reg];
        #pragma unroll
        for (int nt = 0; nt < 4; ++nt) {
            const float x = acc[nt][reg] * inv;
            outb[(size_t)i * FO_ + nt * 16 + lm] = (x > 0.f) ? x : expm1f(x);
        }
    }
}

extern "C" void kernel_launch(void* const* d_in, const int* in_sizes, int n_in,
                              void* d_out, int out_size, void* d_ws, size_t ws_size,
                              hipStream_t stream) {
    const float* input = (const float*)d_in[0];   // [64][1024][256] f32
    const int*   adj   = (const int*)d_in[1];     // [64][1024][1024] i32
    const float* W     = (const float*)d_in[2];   // [256][64] f32
    const float* a     = (const float*)d_in[3];   // [128] f32
    float* out = (float*)d_out;                   // [64][1024][64] f32

    char* ws = (char*)d_ws;
    unsigned short* hbT   = (unsigned short*)(ws);                        // 8 MiB
    unsigned short* hrT   = (unsigned short*)(ws + (8u  << 20));          // 8 MiB
    float*          c1T   = (float*)(ws + (16u << 20));                   // 16 MiB
    float*          e2    = (float*)(ws + (32u << 20));                   // 256 KiB
    unsigned short* WTfhi = (unsigned short*)(ws + (32u << 20) + (256u << 10));
    unsigned short* WTflo = WTfhi + FIN_ * FO_;

    k0_wt   <<<dim3(64),             dim3(256), 0, stream>>>(W, WTfhi, WTflo);
    k1_hproj<<<dim3((B_ * N_) / 64), dim3(256), 0, stream>>>(input, WTfhi, WTflo, a,
                                                             hbT, hrT, c1T, e2);
    k2_attn <<<dim3(1024),           dim3(256), 0, stream>>>(hbT, hrT, c1T, adj, e2, out);
}